// Round 1
// baseline (273.767 us; speedup 1.0000x reference)
//
#include <hip/hip_runtime.h>
#include <hip/hip_bf16.h>

typedef __bf16 bf16x8 __attribute__((ext_vector_type(8)));
typedef float f32x4 __attribute__((ext_vector_type(4)));
typedef unsigned short ushort_t;
typedef unsigned short ushort8 __attribute__((ext_vector_type(8)));

#define DEVI __device__ __forceinline__

static constexpr int KDIM = 1024;   // d_model
static constexpr int SEQ  = 2048;
static constexpr int NH   = 16;
static constexpr size_t TEN = 4194304; // 4096*1024 elements per tensor

DEVI ushort_t f2bf(float f) {
  union { float f; unsigned u; } a; a.f = f;
  unsigned u = a.u;
  return (ushort_t)((u + 0x7FFFu + ((u >> 16) & 1u)) >> 16);
}

DEVI void gload16(const ushort_t* g, ushort_t* l) {
  __builtin_amdgcn_global_load_lds(
      (const __attribute__((address_space(1))) void*)g,
      (__attribute__((address_space(3))) void*)l,
      16, 0, 0);
}

// ---------------- casts ----------------
__global__ void cast_x_kernel(const float* __restrict__ in, ushort_t* __restrict__ out) {
  const int i = blockIdx.x * 256 + threadIdx.x;   // one float4 each, exact cover
  const float4 v = ((const float4*)in)[i];
  ushort4 o;
  o.x = f2bf(v.x); o.y = f2bf(v.y); o.z = f2bf(v.z); o.w = f2bf(v.w);
  ((ushort4*)out)[i] = o;
}

__global__ void cast_w4_kernel(const float* __restrict__ w0, const float* __restrict__ w1,
                               const float* __restrict__ w2, const float* __restrict__ w3,
                               ushort_t* __restrict__ out) {
  const int i = blockIdx.x * 256 + threadIdx.x;   // [0, 1048576) float4s over 4 matrices
  const int which = i >> 18;                      // 262144 float4 per 1024x1024 matrix
  const float* w = which == 0 ? w0 : which == 1 ? w1 : which == 2 ? w2 : w3;
  const float4 v = ((const float4*)w)[i & 262143];
  ushort4 o;
  o.x = f2bf(v.x); o.y = f2bf(v.y); o.z = f2bf(v.z); o.w = f2bf(v.w);
  ((ushort4*)out)[i] = o;
}

// ---------------- GEMM: C = A(M,K) * B(N,K)^T, bf16 in, 128x128 tile ----------------
// MODE 0: QKV fused (N=3072), scatter-store bf16 into (b,h,s,d) per tensor
// MODE 1: fp32 row-major store (output projection)
template<int MODE>
__global__ __launch_bounds__(256, 2) void gemm128(const ushort_t* __restrict__ A,
                                                  const ushort_t* __restrict__ Bm,
                                                  ushort_t* __restrict__ obf,
                                                  float* __restrict__ ofp) {
  __shared__ ushort_t smA[128 * 64];
  __shared__ ushort_t smB[128 * 64];
  const int tid = threadIdx.x;
  const int w = tid >> 6, l = tid & 63;
  const int lg = l >> 4, ll = l & 15;
  const int lr = l >> 3, lc = (l & 7) * 8;
  const int m0 = blockIdx.y * 128, n0 = blockIdx.x * 128;
  const int wm = (w >> 1) * 64, wn = (w & 1) * 64;

  f32x4 acc[4][4];
#pragma unroll
  for (int i = 0; i < 4; ++i)
#pragma unroll
    for (int j = 0; j < 4; ++j) acc[i][j] = f32x4{0.f, 0.f, 0.f, 0.f};

  for (int k0 = 0; k0 < KDIM; k0 += 64) {
    __syncthreads();
#pragma unroll
    for (int i = 0; i < 4; ++i) {
      const int ci = w * 4 + i;   // 16 chunks of 1KB per 16KB tile
      gload16(A  + (size_t)(m0 + ci * 8 + lr) * KDIM + k0 + lc, smA + ci * 512);
      gload16(Bm + (size_t)(n0 + ci * 8 + lr) * KDIM + k0 + lc, smB + ci * 512);
    }
    __syncthreads();
#pragma unroll
    for (int ks = 0; ks < 2; ++ks) {
      bf16x8 af[4], bf[4];
#pragma unroll
      for (int t = 0; t < 4; ++t) {
        af[t] = *(const bf16x8*)(smA + (wm + t * 16 + ll) * 64 + ks * 32 + lg * 8);
        bf[t] = *(const bf16x8*)(smB + (wn + t * 16 + ll) * 64 + ks * 32 + lg * 8);
      }
#pragma unroll
      for (int i = 0; i < 4; ++i)
#pragma unroll
        for (int j = 0; j < 4; ++j)
          acc[i][j] = __builtin_amdgcn_mfma_f32_16x16x32_bf16(af[i], bf[j], acc[i][j], 0, 0, 0);
    }
  }

#pragma unroll
  for (int i = 0; i < 4; ++i) {
#pragma unroll
    for (int j = 0; j < 4; ++j) {
#pragma unroll
      for (int r = 0; r < 4; ++r) {
        const int gm = m0 + wm + i * 16 + 4 * lg + r;
        const int gn = n0 + wn + j * 16 + ll;
        const float v = acc[i][j][r];
        if (MODE == 0) {
          const int which = gn >> 10, nn = gn & 1023;
          const int h = nn >> 6, d = nn & 63;
          const int b = gm >> 11, s = gm & 2047;
          obf[(size_t)which * TEN + (((size_t)(b * NH + h) * SEQ + s) * 64 + d)] = f2bf(v);
        } else {
          ofp[(size_t)gm * 1024 + gn] = v;
        }
      }
    }
  }
}

// ---------------- V transpose: (bh, s, d) -> (bh, d, s) ----------------
__global__ __launch_bounds__(256) void transpose_v(const ushort_t* __restrict__ V,
                                                   ushort_t* __restrict__ Vt) {
  __shared__ ushort_t t[64][72];
  const int bh = blockIdx.x, sc_ = blockIdx.y;
  const ushort_t* src = V + (size_t)bh * SEQ * 64 + (size_t)sc_ * 64 * 64;
  ushort_t* dst = Vt + (size_t)bh * SEQ * 64 + sc_ * 64;
  const int r = threadIdx.x >> 3, c0 = (threadIdx.x & 7) * 8;
#pragma unroll
  for (int i = 0; i < 2; ++i) {
    const int s_ = r + i * 32;
    *(ushort8*)(&t[s_][c0]) = *(const ushort8*)(src + s_ * 64 + c0);
  }
  __syncthreads();
#pragma unroll
  for (int i = 0; i < 2; ++i) {
    const int d = r + i * 32;
    ushort8 v;
#pragma unroll
    for (int e = 0; e < 8; ++e) v[e] = t[c0 + e][d];
    *(ushort8*)(dst + (size_t)d * SEQ + c0) = v;
  }
}

// ---------------- causal flash attention ----------------
// grid: (S/128, B*H). 4 waves x 32 Q-rows. KV tile = 64.
__global__ __launch_bounds__(256, 2) void attn_fwd(const ushort_t* __restrict__ Qg,
                                                   const ushort_t* __restrict__ Kg,
                                                   const ushort_t* __restrict__ Vtg,
                                                   ushort_t* __restrict__ ao) {
  __shared__ ushort_t Ks[64 * 64];      // [kv][d]
  __shared__ ushort_t Vs[64 * 64];      // [d][kv]  (from pre-transposed V)
  __shared__ ushort_t Ps[4][32 * 64];   // per-wave P tile [q][kv]
  const int tid = threadIdx.x;
  const int w = tid >> 6, l = tid & 63;
  const int lg = l >> 4, ll = l & 15;
  const int lr = l >> 3, lc = (l & 7) * 8;
  const int bh = blockIdx.y;
  const int q0 = blockIdx.x * 128;
  const ushort_t* Qb = Qg + (size_t)bh * SEQ * 64;
  const ushort_t* Kb = Kg + (size_t)bh * SEQ * 64;
  const ushort_t* Vb = Vtg + (size_t)bh * SEQ * 64;

  // Q fragments held in registers for the whole block
  bf16x8 qf[2][2];
#pragma unroll
  for (int qg = 0; qg < 2; ++qg)
#pragma unroll
    for (int ks = 0; ks < 2; ++ks)
      qf[qg][ks] = *(const bf16x8*)(Qb + (size_t)(q0 + w * 32 + qg * 16 + ll) * 64 + ks * 32 + lg * 8);

  f32x4 o[2][4];
  float mi[2][4], li[2][4];
#pragma unroll
  for (int qg = 0; qg < 2; ++qg) {
#pragma unroll
    for (int dg = 0; dg < 4; ++dg) o[qg][dg] = f32x4{0.f, 0.f, 0.f, 0.f};
#pragma unroll
    for (int r = 0; r < 4; ++r) { mi[qg][r] = -3.0e38f; li[qg][r] = 0.f; }
  }

  const int nkt = q0 / 64 + 2;   // causal: tiles 0 .. (q0+128)/64 - 1
  for (int kt = 0; kt < nkt; ++kt) {
    const int kv0 = kt * 64;
    __syncthreads();
#pragma unroll
    for (int i = 0; i < 2; ++i) {
      const int ci = w * 2 + i;   // 8 chunks of 1KB per 8KB tile
      gload16(Kb + (size_t)(kv0 + ci * 8 + lr) * 64 + lc, Ks + ci * 512);
      gload16(Vb + (size_t)(ci * 8 + lr) * SEQ + kv0 + lc, Vs + ci * 512);
    }
    __syncthreads();

    // scores: S[q][kv] = Q . K^T
    f32x4 sc[2][4];
#pragma unroll
    for (int qg = 0; qg < 2; ++qg)
#pragma unroll
      for (int ng = 0; ng < 4; ++ng) sc[qg][ng] = f32x4{0.f, 0.f, 0.f, 0.f};
#pragma unroll
    for (int ng = 0; ng < 4; ++ng)
#pragma unroll
      for (int ks = 0; ks < 2; ++ks) {
        const bf16x8 kf = *(const bf16x8*)(Ks + (ng * 16 + ll) * 64 + ks * 32 + lg * 8);
        sc[0][ng] = __builtin_amdgcn_mfma_f32_16x16x32_bf16(qf[0][ks], kf, sc[0][ng], 0, 0, 0);
        sc[1][ng] = __builtin_amdgcn_mfma_f32_16x16x32_bf16(qf[1][ks], kf, sc[1][ng], 0, 0, 0);
      }

    // mask + scale + online softmax (rows live in 16-lane groups)
#pragma unroll
    for (int qg = 0; qg < 2; ++qg) {
#pragma unroll
      for (int r = 0; r < 4; ++r) {
        const int qrow = q0 + w * 32 + qg * 16 + 4 * lg + r;
        float mx = -3.0e38f;
#pragma unroll
        for (int ng = 0; ng < 4; ++ng) {
          float v = sc[qg][ng][r] * 0.125f;
          const int kvc = kv0 + ng * 16 + ll;
          v = (kvc <= qrow) ? v : -3.0e38f;
          sc[qg][ng][r] = v;
          mx = fmaxf(mx, v);
        }
        mx = fmaxf(mx, __shfl_xor(mx, 1));
        mx = fmaxf(mx, __shfl_xor(mx, 2));
        mx = fmaxf(mx, __shfl_xor(mx, 4));
        mx = fmaxf(mx, __shfl_xor(mx, 8));
        const float mnew = fmaxf(mi[qg][r], mx);
        const float alpha = __expf(mi[qg][r] - mnew);
        float ps = 0.f;
#pragma unroll
        for (int ng = 0; ng < 4; ++ng) {
          const float p = __expf(sc[qg][ng][r] - mnew);
          Ps[w][(qg * 16 + 4 * lg + r) * 64 + ng * 16 + ll] = f2bf(p);
          ps += p;
        }
        ps += __shfl_xor(ps, 1);
        ps += __shfl_xor(ps, 2);
        ps += __shfl_xor(ps, 4);
        ps += __shfl_xor(ps, 8);
        li[qg][r] = li[qg][r] * alpha + ps;
        mi[qg][r] = mnew;
#pragma unroll
        for (int dg = 0; dg < 4; ++dg) o[qg][dg][r] *= alpha;
      }
    }

    // PV: O += P(32xKT) * V(KTx64); P via per-wave LDS (in-order DS pipe, no barrier)
    bf16x8 pf[2][2];
#pragma unroll
    for (int qg = 0; qg < 2; ++qg)
#pragma unroll
      for (int ks = 0; ks < 2; ++ks)
        pf[qg][ks] = *(const bf16x8*)(&Ps[w][(qg * 16 + ll) * 64 + ks * 32 + lg * 8]);
#pragma unroll
    for (int dg = 0; dg < 4; ++dg)
#pragma unroll
      for (int ks = 0; ks < 2; ++ks) {
        const bf16x8 vf = *(const bf16x8*)(Vs + (dg * 16 + ll) * 64 + ks * 32 + lg * 8);
        o[0][dg] = __builtin_amdgcn_mfma_f32_16x16x32_bf16(pf[0][ks], vf, o[0][dg], 0, 0, 0);
        o[1][dg] = __builtin_amdgcn_mfma_f32_16x16x32_bf16(pf[1][ks], vf, o[1][dg], 0, 0, 0);
      }
  }

  // epilogue: normalize, store to (b, s, h*64+d)
  const int b = bh >> 4, h = bh & 15;
#pragma unroll
  for (int qg = 0; qg < 2; ++qg)
#pragma unroll
    for (int dg = 0; dg < 4; ++dg)
#pragma unroll
      for (int r = 0; r < 4; ++r) {
        const int s_ = q0 + w * 32 + qg * 16 + 4 * lg + r;
        const float v = o[qg][dg][r] / li[qg][r];
        ao[((size_t)b * SEQ + s_) * 1024 + h * 64 + dg * 16 + ll] = f2bf(v);
      }
}

// ---------------- launch ----------------
extern "C" void kernel_launch(void* const* d_in, const int* in_sizes, int n_in,
                              void* d_out, int out_size, void* d_ws, size_t ws_size,
                              hipStream_t stream) {
  (void)in_sizes; (void)n_in; (void)out_size; (void)ws_size;
  const float* x  = (const float*)d_in[0];
  const float* wq = (const float*)d_in[1];
  const float* wk = (const float*)d_in[2];
  const float* wv = (const float*)d_in[3];
  const float* wo = (const float*)d_in[4];

  char* ws = (char*)d_ws;
  ushort_t* xb  = (ushort_t*)ws;                     // 8 MiB; reused as attn-out after QKV GEMM
  ushort_t* wb  = (ushort_t*)(ws + (8u  << 20));     // 8 MiB: Wq,Wk,Wv,Wo bf16 contiguous
  ushort_t* qkv = (ushort_t*)(ws + (16u << 20));     // 24 MiB: Q,K,V in (b,h,s,d)
  ushort_t* vt  = (ushort_t*)(ws + (40u << 20));     // 8 MiB: V^T in (b,h,d,s)
  ushort_t* ao  = xb;                                // attention output (b,s,h*64+d)
  float* out = (float*)d_out;

  cast_x_kernel <<<4096, 256, 0, stream>>>(x, xb);
  cast_w4_kernel<<<4096, 256, 0, stream>>>(wq, wk, wv, wo, wb);
  gemm128<0><<<dim3(24, 32), 256, 0, stream>>>(xb, wb, qkv, nullptr);
  transpose_v<<<dim3(32, 32), 256, 0, stream>>>(qkv + 2 * TEN, vt);
  attn_fwd  <<<dim3(16, 32), 256, 0, stream>>>(qkv, qkv + TEN, vt, ao);
  gemm128<1><<<dim3(8, 32), 256, 0, stream>>>(ao, wb + 3 * 1048576, nullptr, out);
}

// Round 2
// 211.754 us; speedup vs baseline: 1.2929x; 1.2929x over previous
//
#include <hip/hip_runtime.h>
#include <hip/hip_bf16.h>

typedef __bf16 bf16x8 __attribute__((ext_vector_type(8)));
typedef float f32x4 __attribute__((ext_vector_type(4)));
typedef unsigned short ushort_t;
typedef unsigned short ushort8 __attribute__((ext_vector_type(8)));

#define DEVI __device__ __forceinline__

static constexpr int KDIM = 1024;   // d_model
static constexpr int SEQ  = 2048;
static constexpr int NH   = 16;
static constexpr size_t TEN = 4194304; // 4096*1024 elements per tensor

DEVI ushort_t f2bf(float f) {
  union { float f; unsigned u; } a; a.f = f;
  unsigned u = a.u;
  return (ushort_t)((u + 0x7FFFu + ((u >> 16) & 1u)) >> 16);
}

DEVI void gload16(const ushort_t* g, ushort_t* l) {
  __builtin_amdgcn_global_load_lds(
      (const __attribute__((address_space(1))) void*)g,
      (__attribute__((address_space(3))) void*)l,
      16, 0, 0);
}

// ---------------- casts ----------------
__global__ void cast_x_kernel(const float* __restrict__ in, ushort_t* __restrict__ out) {
  const int i = blockIdx.x * 256 + threadIdx.x;   // one float4 each, exact cover
  const float4 v = ((const float4*)in)[i];
  ushort4 o;
  o.x = f2bf(v.x); o.y = f2bf(v.y); o.z = f2bf(v.z); o.w = f2bf(v.w);
  ((ushort4*)out)[i] = o;
}

__global__ void cast_w4_kernel(const float* __restrict__ w0, const float* __restrict__ w1,
                               const float* __restrict__ w2, const float* __restrict__ w3,
                               ushort_t* __restrict__ out) {
  const int i = blockIdx.x * 256 + threadIdx.x;   // [0, 1048576) float4s over 4 matrices
  const int which = i >> 18;                      // 262144 float4 per 1024x1024 matrix
  const float* w = which == 0 ? w0 : which == 1 ? w1 : which == 2 ? w2 : w3;
  const float4 v = ((const float4*)w)[i & 262143];
  ushort4 o;
  o.x = f2bf(v.x); o.y = f2bf(v.y); o.z = f2bf(v.z); o.w = f2bf(v.w);
  ((ushort4*)out)[i] = o;
}

// ---------------- GEMM: C = A(M,K) * B(N,K)^T, bf16 in, 128x128 tile ----------------
template<int MODE>
__global__ __launch_bounds__(256, 2) void gemm128(const ushort_t* __restrict__ A,
                                                  const ushort_t* __restrict__ Bm,
                                                  ushort_t* __restrict__ obf,
                                                  float* __restrict__ ofp) {
  __shared__ ushort_t smA[128 * 64];
  __shared__ ushort_t smB[128 * 64];
  const int tid = threadIdx.x;
  const int w = tid >> 6, l = tid & 63;
  const int lg = l >> 4, ll = l & 15;
  const int lr = l >> 3, lc = (l & 7) * 8;
  const int m0 = blockIdx.y * 128, n0 = blockIdx.x * 128;
  const int wm = (w >> 1) * 64, wn = (w & 1) * 64;

  f32x4 acc[4][4];
#pragma unroll
  for (int i = 0; i < 4; ++i)
#pragma unroll
    for (int j = 0; j < 4; ++j) acc[i][j] = f32x4{0.f, 0.f, 0.f, 0.f};

  for (int k0 = 0; k0 < KDIM; k0 += 64) {
    __syncthreads();
#pragma unroll
    for (int i = 0; i < 4; ++i) {
      const int ci = w * 4 + i;
      gload16(A  + (size_t)(m0 + ci * 8 + lr) * KDIM + k0 + lc, smA + ci * 512);
      gload16(Bm + (size_t)(n0 + ci * 8 + lr) * KDIM + k0 + lc, smB + ci * 512);
    }
    __syncthreads();
#pragma unroll
    for (int ks = 0; ks < 2; ++ks) {
      bf16x8 af[4], bfr[4];
#pragma unroll
      for (int t = 0; t < 4; ++t) {
        af[t]  = *(const bf16x8*)(smA + (wm + t * 16 + ll) * 64 + ks * 32 + lg * 8);
        bfr[t] = *(const bf16x8*)(smB + (wn + t * 16 + ll) * 64 + ks * 32 + lg * 8);
      }
#pragma unroll
      for (int i = 0; i < 4; ++i)
#pragma unroll
        for (int j = 0; j < 4; ++j)
          acc[i][j] = __builtin_amdgcn_mfma_f32_16x16x32_bf16(af[i], bfr[j], acc[i][j], 0, 0, 0);
    }
  }

#pragma unroll
  for (int i = 0; i < 4; ++i) {
#pragma unroll
    for (int j = 0; j < 4; ++j) {
#pragma unroll
      for (int r = 0; r < 4; ++r) {
        const int gm = m0 + wm + i * 16 + 4 * lg + r;
        const int gn = n0 + wn + j * 16 + ll;
        const float v = acc[i][j][r];
        if (MODE == 0) {
          const int which = gn >> 10, nn = gn & 1023;
          const int h = nn >> 6, d = nn & 63;
          const int b = gm >> 11, s = gm & 2047;
          obf[(size_t)which * TEN + (((size_t)(b * NH + h) * SEQ + s) * 64 + d)] = f2bf(v);
        } else {
          ofp[(size_t)gm * 1024 + gn] = v;
        }
      }
    }
  }
}

// ---------------- V transpose: (bh, s, d) -> (bh, d, s) ----------------
__global__ __launch_bounds__(256) void transpose_v(const ushort_t* __restrict__ V,
                                                   ushort_t* __restrict__ Vt) {
  __shared__ ushort_t t[64][72];
  const int bh = blockIdx.x, sc_ = blockIdx.y;
  const ushort_t* src = V + (size_t)bh * SEQ * 64 + (size_t)sc_ * 64 * 64;
  ushort_t* dst = Vt + (size_t)bh * SEQ * 64 + sc_ * 64;
  const int r = threadIdx.x >> 3, c0 = (threadIdx.x & 7) * 8;
#pragma unroll
  for (int i = 0; i < 2; ++i) {
    const int s_ = r + i * 32;
    *(ushort8*)(&t[s_][c0]) = *(const ushort8*)(src + s_ * 64 + c0);
  }
  __syncthreads();
#pragma unroll
  for (int i = 0; i < 2; ++i) {
    const int d = r + i * 32;
    ushort8 v;
#pragma unroll
    for (int e = 0; e < 8; ++e) v[e] = t[c0 + e][d];
    *(ushort8*)(dst + (size_t)d * SEQ + c0) = v;
  }
}

// ---------------- causal flash attention v2 ----------------
// grid: (S/64, B*H). 4 waves x 16 Q-rows each. KV tile = 64. dbuf K/V, XOR-swizzled LDS.
__global__ __launch_bounds__(256, 4) void attn_fwd(const ushort_t* __restrict__ Qg,
                                                   const ushort_t* __restrict__ Kg,
                                                   const ushort_t* __restrict__ Vtg,
                                                   ushort_t* __restrict__ ao) {
  __shared__ ushort_t Ks[2][64 * 64];   // [kv][d], col-bytes XOR ((row&7)<<4)
  __shared__ ushort_t Vs[2][64 * 64];   // [d][kv], same swizzle
  __shared__ ushort_t Ps[4][16 * 64];   // per-wave [q][kv], same swizzle
  const int tid = threadIdx.x;
  const int w = tid >> 6, l = tid & 63;
  const int lg = l >> 4, ll = l & 15;
  const int lr = l >> 3, lc = (l & 7) * 8;
  const int bh = blockIdx.y;
  // complementary q-tile pairing: blocks i and i+256 (y differs by 8) get qx and 31-qx
  const int qx = ((blockIdx.y >> 3) & 1) ? (31 - (int)blockIdx.x) : (int)blockIdx.x;
  const int q0 = qx * 64;
  const ushort_t* Qb = Qg  + (size_t)bh * SEQ * 64;
  const ushort_t* Kb = Kg  + (size_t)bh * SEQ * 64;
  const ushort_t* Vb = Vtg + (size_t)bh * SEQ * 64;

  // Q fragments (16 rows per wave), direct from global
  bf16x8 qf[2];
#pragma unroll
  for (int ks = 0; ks < 2; ++ks)
    qf[ks] = *(const bf16x8*)(Qb + (size_t)(q0 + w * 16 + ll) * 64 + ks * 32 + lg * 8);

  f32x4 o[4];
  float mi[4], li[4];
#pragma unroll
  for (int dg = 0; dg < 4; ++dg) o[dg] = f32x4{0.f, 0.f, 0.f, 0.f};
#pragma unroll
  for (int r = 0; r < 4; ++r) { mi[r] = -3.0e38f; li[r] = 0.f; }

  const float SCL2 = 0.18033688011112042f;  // (1/sqrt(64)) * log2(e)
  const int nkt = qx + 1;                   // tiles 0..qx; only kt==qx is masked

  // stage tile 0 into buf 0 (2 K-chunks + 2 V-chunks per wave, swizzled source)
#pragma unroll
  for (int i = 0; i < 2; ++i) {
    const int c = w * 2 + i;
    const int scol = lc ^ (lr * 8);
    gload16(Kb + (size_t)(c * 8 + lr) * 64 + scol, Ks[0] + c * 512);
    gload16(Vb + (size_t)(c * 8 + lr) * SEQ + 0 + scol, Vs[0] + c * 512);
  }
  __syncthreads();

  for (int kt = 0; kt < nkt; ++kt) {
    const int cur = kt & 1;
    if (kt + 1 < nkt) {
      const int kv1 = (kt + 1) * 64;
#pragma unroll
      for (int i = 0; i < 2; ++i) {
        const int c = w * 2 + i;
        const int scol = lc ^ (lr * 8);
        gload16(Kb + (size_t)(kv1 + c * 8 + lr) * 64 + scol, Ks[cur ^ 1] + c * 512);
        gload16(Vb + (size_t)(c * 8 + lr) * SEQ + kv1 + scol, Vs[cur ^ 1] + c * 512);
      }
    }

    // QK^T
    f32x4 sc[4];
#pragma unroll
    for (int ng = 0; ng < 4; ++ng) sc[ng] = f32x4{0.f, 0.f, 0.f, 0.f};
#pragma unroll
    for (int ng = 0; ng < 4; ++ng) {
      const int rr = ng * 16 + ll;
#pragma unroll
      for (int ks = 0; ks < 2; ++ks) {
        const int cb = ks * 32 + lg * 8;
        const bf16x8 kf = *(const bf16x8*)(Ks[cur] + rr * 64 + (cb ^ ((rr & 7) * 8)));
        sc[ng] = __builtin_amdgcn_mfma_f32_16x16x32_bf16(qf[ks], kf, sc[ng], 0, 0, 0);
      }
    }

    // online softmax (exp2 domain); rows live across 16-lane groups
    const bool diag = (kt == qx);
#pragma unroll
    for (int r = 0; r < 4; ++r) {
      float mx = -3.0e38f;
#pragma unroll
      for (int ng = 0; ng < 4; ++ng) {
        float v = sc[ng][r] * SCL2;
        if (diag) {
          const int kvc = ng * 16 + ll;
          const int qr = w * 16 + 4 * lg + r;
          v = (kvc <= qr) ? v : -3.0e38f;
        }
        sc[ng][r] = v;
        mx = fmaxf(mx, v);
      }
      mx = fmaxf(mx, __shfl_xor(mx, 1));
      mx = fmaxf(mx, __shfl_xor(mx, 2));
      mx = fmaxf(mx, __shfl_xor(mx, 4));
      mx = fmaxf(mx, __shfl_xor(mx, 8));
      const float mnew = fmaxf(mi[r], mx);
      const float alpha = __builtin_amdgcn_exp2f(mi[r] - mnew);
      const int pr = 4 * lg + r;
      float ps = 0.f;
#pragma unroll
      for (int ng = 0; ng < 4; ++ng) {
        const float p = __builtin_amdgcn_exp2f(sc[ng][r] - mnew);
        const int pc = ng * 16 + ll;
        Ps[w][pr * 64 + (pc ^ ((pr & 7) * 8))] = f2bf(p);
        ps += p;
      }
      ps += __shfl_xor(ps, 1);
      ps += __shfl_xor(ps, 2);
      ps += __shfl_xor(ps, 4);
      ps += __shfl_xor(ps, 8);
      li[r] = li[r] * alpha + ps;
      mi[r] = mnew;
#pragma unroll
      for (int dg = 0; dg < 4; ++dg) o[dg][r] *= alpha;
    }

    // PV: O += P(16xKT) * Vt(64xKT)^T
    bf16x8 pf[2];
#pragma unroll
    for (int ks = 0; ks < 2; ++ks) {
      const int cb = ks * 32 + lg * 8;
      pf[ks] = *(const bf16x8*)(&Ps[w][ll * 64 + (cb ^ ((ll & 7) * 8))]);
    }
#pragma unroll
    for (int dg = 0; dg < 4; ++dg) {
      const int rr = dg * 16 + ll;
#pragma unroll
      for (int ks = 0; ks < 2; ++ks) {
        const int cb = ks * 32 + lg * 8;
        const bf16x8 vf = *(const bf16x8*)(Vs[cur] + rr * 64 + (cb ^ ((rr & 7) * 8)));
        o[dg] = __builtin_amdgcn_mfma_f32_16x16x32_bf16(pf[ks], vf, o[dg], 0, 0, 0);
      }
    }
    __syncthreads();   // drains vmcnt(0): next tile staged; everyone done with cur
  }

  // epilogue: normalize, store to (b, s, h*64+d)
  const int b = bh >> 4, h = bh & 15;
#pragma unroll
  for (int dg = 0; dg < 4; ++dg)
#pragma unroll
    for (int r = 0; r < 4; ++r) {
      const int s_ = q0 + w * 16 + 4 * lg + r;
      const float v = o[dg][r] / li[r];
      ao[((size_t)b * SEQ + s_) * 1024 + h * 64 + dg * 16 + ll] = f2bf(v);
    }
}

// ---------------- launch ----------------
extern "C" void kernel_launch(void* const* d_in, const int* in_sizes, int n_in,
                              void* d_out, int out_size, void* d_ws, size_t ws_size,
                              hipStream_t stream) {
  (void)in_sizes; (void)n_in; (void)out_size; (void)ws_size;
  const float* x  = (const float*)d_in[0];
  const float* wq = (const float*)d_in[1];
  const float* wk = (const float*)d_in[2];
  const float* wv = (const float*)d_in[3];
  const float* wo = (const float*)d_in[4];

  char* ws = (char*)d_ws;
  ushort_t* xb  = (ushort_t*)ws;                     // 8 MiB; reused as attn-out after QKV GEMM
  ushort_t* wb  = (ushort_t*)(ws + (8u  << 20));     // 8 MiB: Wq,Wk,Wv,Wo bf16 contiguous
  ushort_t* qkv = (ushort_t*)(ws + (16u << 20));     // 24 MiB: Q,K,V in (b,h,s,d)
  ushort_t* vt  = (ushort_t*)(ws + (40u << 20));     // 8 MiB: V^T in (b,h,d,s)
  ushort_t* ao  = xb;                                // attention output (b,s,h*64+d)
  float* out = (float*)d_out;

  cast_x_kernel <<<4096, 256, 0, stream>>>(x, xb);
  cast_w4_kernel<<<4096, 256, 0, stream>>>(wq, wk, wv, wo, wb);
  gemm128<0><<<dim3(24, 32), 256, 0, stream>>>(xb, wb, qkv, nullptr);
  transpose_v<<<dim3(32, 32), 256, 0, stream>>>(qkv + 2 * TEN, vt);
  attn_fwd  <<<dim3(32, 32), 256, 0, stream>>>(qkv, qkv + TEN, vt, ao);
  gemm128<1><<<dim3(8, 32), 256, 0, stream>>>(ao, wb + 3 * 1048576, nullptr, out);
}